// Round 2
// baseline (582.797 us; speedup 1.0000x reference)
//
#include <hip/hip_runtime.h>

#define N_ATOMS 4096
#define FDIM 32
#define HID 512

typedef __bf16 bf16x8 __attribute__((ext_vector_type(8)));
typedef float f32x4 __attribute__((ext_vector_type(4)));

__device__ __forceinline__ float bf2f(ushort h) {
  union { uint u; float f; } v; v.u = ((uint)h) << 16; return v.f;
}
__device__ __forceinline__ ushort f2bf(float f) {
  union { float f; uint u; } v; v.f = f;
  uint u = v.u;
  u += 0x7fffu + ((u >> 16) & 1u);   // RNE
  return (ushort)(u >> 16);
}

// ---- prep_adj: adjb = bf16(adj); rdeg[i] = 1/max(rowsum_f32, 1) -----------
__global__ __launch_bounds__(256) void prep_adj(const float* __restrict__ adj,
                                                ushort* __restrict__ adjb,
                                                float* __restrict__ rdeg) {
  const int row = blockIdx.x;
  const int t = threadIdx.x;
  const float* r = adj + (size_t)row * N_ATOMS;
  ushort* w = adjb + (size_t)row * N_ATOMS;
  float s = 0.f;
#pragma unroll
  for (int i = 0; i < 4; i++) {
    const int c = (t + i * 256) * 4;
    float4 v = *(const float4*)(r + c);
    s += v.x + v.y + v.z + v.w;
    ushort4 o;
    o.x = f2bf(v.x); o.y = f2bf(v.y); o.z = f2bf(v.z); o.w = f2bf(v.w);
    *(ushort4*)(w + c) = o;
  }
#pragma unroll
  for (int off = 32; off; off >>= 1) s += __shfl_down(s, off);
  __shared__ float red[4];
  if ((t & 63) == 0) red[t >> 6] = s;
  __syncthreads();
  if (t == 0) rdeg[row] = 1.f / fmaxf(red[0] + red[1] + red[2] + red[3], 1.f);
}

// ---- xt[c][m] = bf16(x[m][c]) ---------------------------------------------
__global__ __launch_bounds__(256) void prep_x(const float* __restrict__ x,
                                              ushort* __restrict__ xt) {
  const int idx = blockIdx.x * 256 + threadIdx.x;   // 4096*32
  const int m = idx >> 5, c = idx & 31;
  xt[(size_t)c * N_ATOMS + m] = f2bf(x[(size_t)m * FDIM + c]);
}

// ---- wcat2[n][0:512]=Ws2[n], [512:1024]=Wn2[n] (bf16) ---------------------
__global__ __launch_bounds__(256) void prep_w2(const float* __restrict__ ws2,
                                               const float* __restrict__ wn2,
                                               ushort* __restrict__ wcat2) {
  const int idx = blockIdx.x * 256 + threadIdx.x;   // 512*1024
  const int n = idx >> 10, k = idx & 1023;
  float v = (k < 512) ? ws2[(size_t)n * 512 + k] : wn2[(size_t)n * 512 + k - 512];
  wcat2[idx] = f2bf(v);
}

// ---- templated NT MFMA GEMM: C[m,n] = sum_k A[m,k]*Bt[n,k] ----------------
// MODE 0: atomicAdd f32 partials (split-K)     -> Cout = float*
// MODE 1: scale by rdeg[m], bf16 store at ldc/coff
// MODE 2: + bias0[n]+bias1[n] (f32), relu, bf16 store
template<int BM, int BN, int WROWS, int WCOLS, int MODE>
__global__ __launch_bounds__(256) void gemm_nt(
    const ushort* __restrict__ A, int lda,
    const ushort* __restrict__ B, int ldb,
    int Kchunk,
    void* __restrict__ Cout, int ldc, int coff,
    const float* __restrict__ rdeg,
    const float* __restrict__ bias0, const float* __restrict__ bias1)
{
  constexpr int PITCH = 72;          // 64 + 8 bf16 pad; rows stay 16B-aligned
  constexpr int WTM = BM / WROWS;
  constexpr int WTN = BN / WCOLS;
  constexpr int MT = WTM / 16;
  constexpr int NT = WTN / 16;

  __shared__ ushort As[BM * PITCH];
  __shared__ ushort Bs[BN * PITCH];

  const int t = threadIdx.x;
  const int wave = t >> 6;
  const int lane = t & 63;
  const int q = lane >> 4;
  const int ln = lane & 15;
  const int wr = wave / WCOLS;
  const int wc = wave % WCOLS;
  const int mbase = wr * WTM;
  const int nbase = wc * WTN;

  const int n0 = blockIdx.x * BN;
  const int m0 = blockIdx.y * BM;
  const int kbase = blockIdx.z * Kchunk;

  f32x4 acc[MT][NT];
#pragma unroll
  for (int i = 0; i < MT; i++)
#pragma unroll
    for (int j = 0; j < NT; j++)
#pragma unroll
      for (int r = 0; r < 4; r++) acc[i][j][r] = 0.f;

  for (int kt = 0; kt < Kchunk; kt += 64) {
    const int kg = kbase + kt;
#pragma unroll
    for (int i = 0; i < BM / 32; i++) {
      const int g = i * 256 + t;
      const int row = g >> 3;
      const int c8 = g & 7;
      uint4 v = *(const uint4*)(A + (size_t)(m0 + row) * lda + kg + c8 * 8);
      *(uint4*)(&As[row * PITCH + c8 * 8]) = v;
    }
#pragma unroll
    for (int i = 0; i < BN / 32; i++) {
      const int g = i * 256 + t;
      const int row = g >> 3;
      const int c8 = g & 7;
      uint4 v = *(const uint4*)(B + (size_t)(n0 + row) * ldb + kg + c8 * 8);
      *(uint4*)(&Bs[row * PITCH + c8 * 8]) = v;
    }
    __syncthreads();
#pragma unroll
    for (int kk = 0; kk < 64; kk += 32) {
      bf16x8 af[MT], bfr[NT];
#pragma unroll
      for (int i = 0; i < MT; i++)
        af[i] = *(const bf16x8*)(&As[(mbase + i * 16 + ln) * PITCH + kk + q * 8]);
#pragma unroll
      for (int j = 0; j < NT; j++)
        bfr[j] = *(const bf16x8*)(&Bs[(nbase + j * 16 + ln) * PITCH + kk + q * 8]);
#pragma unroll
      for (int i = 0; i < MT; i++)
#pragma unroll
        for (int j = 0; j < NT; j++)
          acc[i][j] = __builtin_amdgcn_mfma_f32_16x16x32_bf16(af[i], bfr[j], acc[i][j], 0, 0, 0);
    }
    __syncthreads();
  }

#pragma unroll
  for (int i = 0; i < MT; i++) {
#pragma unroll
    for (int j = 0; j < NT; j++) {
#pragma unroll
      for (int r = 0; r < 4; r++) {
        const int m = m0 + mbase + i * 16 + q * 4 + r;   // C/D: row=(lane>>4)*4+reg
        const int n = n0 + nbase + j * 16 + ln;          //      col=lane&15
        float v = acc[i][j][r];
        if (MODE == 0) {
          atomicAdd((float*)Cout + (size_t)m * ldc + n, v);
        } else if (MODE == 1) {
          v *= rdeg[m];
          ((ushort*)Cout)[(size_t)m * ldc + coff + n] = f2bf(v);
        } else {
          v += bias0[n] + bias1[n];
          v = fmaxf(v, 0.f);
          ((ushort*)Cout)[(size_t)m * ldc + coff + n] = f2bf(v);
        }
      }
    }
  }
}

// ---- h1 = relu(x Ws1^T + (agg1*rdeg) Wn1^T + b) (all f32 in, bf16 out) ----
__global__ __launch_bounds__(256) void h1_kernel(
    const float* __restrict__ x, const float* __restrict__ agg1,
    const float* __restrict__ rdeg,
    const float* __restrict__ ws1, const float* __restrict__ bs1,
    const float* __restrict__ wn1, const float* __restrict__ bn1,
    ushort* __restrict__ cat2, ushort* __restrict__ h1t)
{
  const int idx = blockIdx.x * 256 + threadIdx.x;   // 4096*512
  const int m = idx >> 9;
  const int n = idx & 511;
  const float* xr = x + (size_t)m * FDIM;
  const float* ar = agg1 + (size_t)m * FDIM;
  const float* w1 = ws1 + (size_t)n * FDIM;
  const float* w2 = wn1 + (size_t)n * FDIM;
  float accs = 0.f, accn = 0.f;
#pragma unroll
  for (int k = 0; k < FDIM; k += 4) {
    float4 xv = *(const float4*)(xr + k);
    float4 av = *(const float4*)(ar + k);
    float4 wv = *(const float4*)(w1 + k);
    float4 nv = *(const float4*)(w2 + k);
    accs += xv.x * wv.x + xv.y * wv.y + xv.z * wv.z + xv.w * wv.w;
    accn += av.x * nv.x + av.y * nv.y + av.z * nv.z + av.w * nv.w;
  }
  float v = fmaxf(accs + accn * rdeg[m] + bs1[n] + bn1[n], 0.f);
  ushort h = f2bf(v);
  cat2[(size_t)m * 1024 + n] = h;
  h1t[(size_t)n * N_ATOMS + m] = h;
}

// ---- heads: atom logits (f32 out) + bond a/b vectors ----------------------
__global__ __launch_bounds__(256) void heads_kernel(
    const ushort* __restrict__ h2,
    const float* __restrict__ w_atom, const float* __restrict__ b_atom,
    const float* __restrict__ w_bond,
    float* __restrict__ atom_out,
    float* __restrict__ a_buf, float* __restrict__ b_buf)
{
  const int idx = blockIdx.x * 256 + threadIdx.x;
  if (idx >= N_ATOMS * 40) return;
  const int m = idx / 40;
  const int c = idx - m * 40;
  const ushort* hr = h2 + (size_t)m * HID;
  const float* wr;
  if (c < 32)      wr = w_atom + (size_t)c * HID;
  else if (c < 36) wr = w_bond + (size_t)(c - 32) * 1024;        // a: W[:, :H]
  else             wr = w_bond + (size_t)(c - 36) * 1024 + 512;  // b: W[:, H:]
  float acc = 0.f;
#pragma unroll 4
  for (int k = 0; k < HID; k += 8) {
    uint4 hv = *(const uint4*)(hr + k);
    const ushort* ph = (const ushort*)&hv;
    float4 w0 = *(const float4*)(wr + k);
    float4 w1 = *(const float4*)(wr + k + 4);
    acc += bf2f(ph[0]) * w0.x + bf2f(ph[1]) * w0.y + bf2f(ph[2]) * w0.z + bf2f(ph[3]) * w0.w
         + bf2f(ph[4]) * w1.x + bf2f(ph[5]) * w1.y + bf2f(ph[6]) * w1.z + bf2f(ph[7]) * w1.w;
  }
  if (c < 32)      atom_out[(size_t)m * 32 + c] = acc + b_atom[c];
  else if (c < 36) a_buf[(size_t)m * 4 + (c - 32)] = acc;
  else             b_buf[(size_t)m * 4 + (c - 36)] = acc;
}

// ---- bond fill: out[i][j][0:4] (f32), diagonal explicitly zeroed ----------
__global__ __launch_bounds__(256) void bond_fill(
    const float* __restrict__ av, const float* __restrict__ bv,
    const float* __restrict__ bbond, float* __restrict__ out)
{
  const int idx = blockIdx.x * 256 + threadIdx.x;  // 4096*4096
  const int i = idx >> 12;
  const int j = idx & 4095;
  float4 r;
  if (i < j) {
    float4 ai = *(const float4*)(av + (size_t)i * 4);
    float4 bj = *(const float4*)(bv + (size_t)j * 4);
    r.x = ai.x + bj.x + bbond[0]; r.y = ai.y + bj.y + bbond[1];
    r.z = ai.z + bj.z + bbond[2]; r.w = ai.w + bj.w + bbond[3];
  } else if (i > j) {
    float4 aj = *(const float4*)(av + (size_t)j * 4);
    float4 bi = *(const float4*)(bv + (size_t)i * 4);
    r.x = aj.x + bi.x + bbond[0]; r.y = aj.y + bi.y + bbond[1];
    r.z = aj.z + bi.z + bbond[2]; r.w = aj.w + bi.w + bbond[3];
  } else {
    r.x = r.y = r.z = r.w = 0.f;   // diagonal stays zero (d_out is poisoned!)
  }
  *(float4*)(out + (size_t)idx * 4) = r;
}

extern "C" void kernel_launch(void* const* d_in, const int* in_sizes, int n_in,
                              void* d_out, int out_size, void* d_ws, size_t ws_size,
                              hipStream_t stream)
{
  const float* x        = (const float*)d_in[0];
  const float* adj      = (const float*)d_in[1];
  const float* w_self1  = (const float*)d_in[2];
  const float* b_self1  = (const float*)d_in[3];
  const float* w_neigh1 = (const float*)d_in[4];
  const float* b_neigh1 = (const float*)d_in[5];
  const float* w_self2  = (const float*)d_in[6];
  const float* b_self2  = (const float*)d_in[7];
  const float* w_neigh2 = (const float*)d_in[8];
  const float* b_neigh2 = (const float*)d_in[9];
  const float* w_atom   = (const float*)d_in[10];
  const float* b_atom   = (const float*)d_in[11];
  const float* w_bond   = (const float*)d_in[12];
  const float* b_bond   = (const float*)d_in[13];

  char* w = (char*)d_ws;
  float*  rdeg  = (float*)w;  w += (size_t)N_ATOMS * sizeof(float);
  float*  agg1  = (float*)w;  w += (size_t)N_ATOMS * FDIM * sizeof(float);
  float*  a_buf = (float*)w;  w += (size_t)N_ATOMS * 4 * sizeof(float);
  float*  b_buf = (float*)w;  w += (size_t)N_ATOMS * 4 * sizeof(float);
  ushort* adjb  = (ushort*)w; w += (size_t)N_ATOMS * N_ATOMS * sizeof(ushort);
  ushort* xt    = (ushort*)w; w += (size_t)FDIM * N_ATOMS * sizeof(ushort);
  ushort* h1t   = (ushort*)w; w += (size_t)HID * N_ATOMS * sizeof(ushort);
  ushort* cat2  = (ushort*)w; w += (size_t)N_ATOMS * 1024 * sizeof(ushort);
  ushort* h2    = (ushort*)w; w += (size_t)N_ATOMS * HID * sizeof(ushort);
  ushort* wcat2 = (ushort*)w; w += (size_t)HID * 1024 * sizeof(ushort);

  float* atom_out = (float*)d_out;
  float* bond_out = (float*)d_out + (size_t)N_ATOMS * FDIM;

  prep_adj<<<N_ATOMS, 256, 0, stream>>>(adj, adjb, rdeg);
  prep_x<<<(N_ATOMS * FDIM) / 256, 256, 0, stream>>>(x, xt);
  prep_w2<<<(HID * 1024) / 256, 256, 0, stream>>>(w_self2, w_neigh2, wcat2);
  hipMemsetAsync(agg1, 0, (size_t)N_ATOMS * FDIM * sizeof(float), stream);
  // agg1 partials: M=4096 N=32 K=4096, split-K=8 -> 256 blocks
  gemm_nt<128, 32, 4, 1, 0><<<dim3(1, 32, 8), 256, 0, stream>>>(
      adjb, N_ATOMS, xt, N_ATOMS, 512, agg1, FDIM, 0, nullptr, nullptr, nullptr);
  h1_kernel<<<(N_ATOMS * HID) / 256, 256, 0, stream>>>(
      x, agg1, rdeg, w_self1, b_self1, w_neigh1, b_neigh1, cat2, h1t);
  // agg2 = (adj @ h1)/deg -> cat2[:, 512:1024]; M=4096 N=512 K=4096, 256 blocks
  gemm_nt<128, 64, 2, 2, 1><<<dim3(8, 32, 1), 256, 0, stream>>>(
      adjb, N_ATOMS, h1t, N_ATOMS, N_ATOMS, cat2, 1024, 512, rdeg, nullptr, nullptr);
  // h2 = relu(cat2 @ [Ws2|Wn2]^T + b); M=4096 N=512 K=1024, 256 blocks
  gemm_nt<128, 64, 2, 2, 2><<<dim3(8, 32, 1), 256, 0, stream>>>(
      cat2, 1024, wcat2, 1024, 1024, h2, HID, 0, nullptr, b_self2, b_neigh2);
  heads_kernel<<<(N_ATOMS * 40 + 255) / 256, 256, 0, stream>>>(
      h2, w_atom, b_atom, w_bond, atom_out, a_buf, b_buf);
  bond_fill<<<(N_ATOMS * N_ATOMS) / 256, 256, 0, stream>>>(a_buf, b_buf, b_bond, bond_out);
}